// Round 1
// baseline (1483.755 us; speedup 1.0000x reference)
//
#include <hip/hip_runtime.h>
#include <hip/hip_bf16.h>
#include <stdint.h>

#define H 256
#define G 4096
#define TILE 64

typedef __attribute__((ext_vector_type(8))) short bf16x8;
typedef __attribute__((ext_vector_type(4))) float f32x4;

__device__ inline short f2bf(float f){
  union { float f; uint32_t u; } v; v.f = f;
  uint32_t r = (v.u + 0x7FFFu + ((v.u >> 16) & 1u)) >> 16;
  return (short)(uint16_t)r;
}
__device__ inline float bf2f(short s){
  union { float f; uint32_t u; } v; v.u = ((uint32_t)(uint16_t)s) << 16;
  return v.f;
}
__device__ inline float sigmoidf_(float x){ return 1.f / (1.f + __expf(-x)); }

// ---------------- weight conversion f32 -> bf16 ----------------
__global__ void conv_w(const float* __restrict__ w1, const float* __restrict__ wih,
                       const float* __restrict__ whh,
                       short* __restrict__ o1, short* __restrict__ oih, short* __restrict__ ohh){
  int i = blockIdx.x * 256 + threadIdx.x;
  if (i < H*H) o1[i] = f2bf(w1[i]);
  if (i < 3*H*H){ oih[i] = f2bf(wih[i]); ohh[i] = f2bf(whh[i]); }
}

// ---------------- K0: initial mean-pool sums + counts ----------------
__global__ __launch_bounds__(256) void k0_pool(const float* __restrict__ x, const int* __restrict__ batch,
                                               float* __restrict__ pool, float* __restrict__ counts, int nNodes){
  __shared__ int ng[TILE];
  const int base = blockIdx.x * TILE;
  const int t = threadIdx.x;
  if (t < TILE) ng[t] = (base + t < nNodes) ? batch[base + t] : -1;
  __syncthreads();
  float acc = 0.f;
  int cur = ng[0];
  for (int i = 0; i < TILE; ++i){
    int g = ng[i];
    if (g < 0) break;
    if (g != cur){ atomicAdd(&pool[(size_t)cur*H + t], acc); acc = 0.f; cur = g; }
    acc += x[(size_t)(base + i)*H + t];
  }
  atomicAdd(&pool[(size_t)cur*H + t], acc);
  if (t < TILE && ng[t] >= 0) atomicAdd(&counts[ng[t]], 1.0f);
}

// ---------------- K0b: repr = pool / max(counts,1) ----------------
__global__ void k0b_div(const float* __restrict__ pool, const float* __restrict__ counts,
                        float* __restrict__ repr){
  size_t i = (size_t)blockIdx.x * 256 + threadIdx.x;
  int g = (int)(i >> 8);
  repr[i] = pool[i] / fmaxf(counts[g], 1.f);
}

// ---------------- K1: fused gate MLP + weighted pooling ----------------
// pool += sum_i gate_i * bf16(x_i + r_g);  gatesum[g] += gate_i
// (correction  new_repr = (pool - gatesum*r)/cnt  applied in K2)
__global__ __launch_bounds__(256) void k1_gate(const float* __restrict__ x, const int* __restrict__ batch,
    const float* __restrict__ repr, const short* __restrict__ w1bf,
    const float* __restrict__ b1, const float* __restrict__ w2, const float* __restrict__ b2p,
    float* __restrict__ pool, float* __restrict__ gatesum, int nNodes){

  __shared__ short Ain[TILE][H + 8];     // g_in bf16, padded row (264)
  __shared__ short Bt[H][40];            // W1 K-chunk: [n][k0..k0+31], padded to 40
  __shared__ float b1s[H], w2s[H];
  __shared__ float gates[TILE];
  __shared__ int   ng[TILE];

  const int t    = threadIdx.x;
  const int wid  = t >> 6;
  const int lane = t & 63;
  const int l15  = lane & 15;
  const int l4   = lane >> 4;
  const int base = blockIdx.x * TILE;
  const float b2v = b2p[0];

  b1s[t] = b1[t];
  w2s[t] = w2[t];
  if (t < TILE){
    int node = base + t;
    ng[t] = (node < nNodes) ? batch[node] : -1;
  }
  __syncthreads();

  // stage g_in = bf16(x + repr[batch])
  for (int u = t; u < TILE*32; u += 256){
    int row = u >> 5, cg = u & 31;
    int c0 = cg * 8;
    int node = base + row;
    bf16x8 o;
    if (node < nNodes){
      int g = ng[row];
      const float4* xp = (const float4*)(x + (size_t)node*H + c0);
      const float4* rp = (const float4*)(repr + (size_t)g*H + c0);
      float4 x0 = xp[0], x1 = xp[1];
      float4 r0 = rp[0], r1 = rp[1];
      o[0]=f2bf(x0.x+r0.x); o[1]=f2bf(x0.y+r0.y); o[2]=f2bf(x0.z+r0.z); o[3]=f2bf(x0.w+r0.w);
      o[4]=f2bf(x1.x+r1.x); o[5]=f2bf(x1.y+r1.y); o[6]=f2bf(x1.z+r1.z); o[7]=f2bf(x1.w+r1.w);
    } else {
      o = (bf16x8)0;
    }
    *(bf16x8*)(&Ain[row][c0]) = o;
  }

  f32x4 acc[16];
  #pragma unroll
  for (int i = 0; i < 16; ++i) acc[i] = (f32x4){0.f,0.f,0.f,0.f};

  for (int kc = 0; kc < 8; ++kc){
    __syncthreads();
    // stage W1 chunk as Bt[n][k]: coalesced 16B units
    for (int u = t; u < 1024; u += 256){
      int n = u >> 2, j8 = (u & 3) * 8;
      bf16x8 v = *(const bf16x8*)(w1bf + (size_t)n*H + kc*32 + j8);
      *(bf16x8*)(&Bt[n][j8]) = v;
    }
    __syncthreads();
    bf16x8 a = *(bf16x8*)(&Ain[wid*16 + l15][kc*32 + l4*8]);
    #pragma unroll
    for (int nt = 0; nt < 16; ++nt){
      bf16x8 b = *(bf16x8*)(&Bt[nt*16 + l15][l4*8]);
      acc[nt] = __builtin_amdgcn_mfma_f32_16x16x32_bf16(a, b, acc[nt], 0, 0, 0);
    }
  }

  // epilogue: s = sum_c w2[c]*relu(h[c]+b1[c]) ; gate = sigmoid(s + b2)
  float part[4] = {0.f,0.f,0.f,0.f};
  #pragma unroll
  for (int nt = 0; nt < 16; ++nt){
    int col = nt*16 + l15;
    float b1v = b1s[col], w2v = w2s[col];
    #pragma unroll
    for (int r = 0; r < 4; ++r){
      float h = fmaxf(acc[nt][r] + b1v, 0.f);
      part[r] += w2v * h;
    }
  }
  #pragma unroll
  for (int off = 1; off < 16; off <<= 1){
    #pragma unroll
    for (int r = 0; r < 4; ++r) part[r] += __shfl_xor(part[r], off);
  }
  if (l15 == 0){
    #pragma unroll
    for (int r = 0; r < 4; ++r){
      int row = wid*16 + l4*4 + r;
      int node = base + row;
      gates[row] = (node < nNodes) ? sigmoidf_(part[r] + b2v) : 0.f;
    }
  }
  __syncthreads();

  // weighted pooling: thread t = column c ; run-length reduce over sorted batch
  {
    float a2 = 0.f;
    int cur = ng[0];
    for (int i = 0; i < TILE; ++i){
      int g = ng[i];
      if (g < 0) break;
      if (g != cur){ atomicAdd(&pool[(size_t)cur*H + t], a2); a2 = 0.f; cur = g; }
      a2 += gates[i] * bf2f(Ain[i][t]);
    }
    atomicAdd(&pool[(size_t)cur*H + t], a2);
  }
  if (t == 0){
    float gs = 0.f;
    int cur = ng[0];
    for (int i = 0; i < TILE; ++i){
      int g = ng[i];
      if (g < 0) break;
      if (g != cur){ atomicAdd(&gatesum[cur], gs); gs = 0.f; cur = g; }
      gs += gates[i];
    }
    atomicAdd(&gatesum[cur], gs);
  }
}

// ---------------- K2: fused GRU over 16 graphs/block ----------------
__global__ __launch_bounds__(256) void k2_gru(const float* __restrict__ pool, const float* __restrict__ gatesum,
    const float* __restrict__ counts, const float* __restrict__ repr_in,
    const short* __restrict__ wihbf, const short* __restrict__ whhbf,
    const float* __restrict__ bih, const float* __restrict__ bhh,
    float* __restrict__ repr_out){

  __shared__ short Anew[16][H + 8];
  __shared__ short Aold[16][H + 8];
  __shared__ float hold[16][H];
  __shared__ float srz[16][2*H];
  __shared__ float sni[16][H];
  __shared__ float snh[16][H];

  const int t    = threadIdx.x;
  const int wid  = t >> 6;
  const int lane = t & 63;
  const int l15  = lane & 15;
  const int l4   = lane >> 4;
  const int g0   = blockIdx.x * 16;

  for (int u = t; u < 16*H; u += 256){
    int row = u >> 8, c = u & 255;
    int g = g0 + row;
    float cnt = fmaxf(counts[g], 1.f);
    float rin = repr_in[(size_t)g*H + c];
    float nr  = (pool[(size_t)g*H + c] - gatesum[g]*rin) / cnt;
    Anew[row][c] = f2bf(nr);
    Aold[row][c] = f2bf(rin);
    hold[row][c] = rin;
  }
  __syncthreads();

  f32x4 ai[12], ah[12];
  #pragma unroll
  for (int i = 0; i < 12; ++i){ ai[i] = (f32x4){0.f,0.f,0.f,0.f}; ah[i] = (f32x4){0.f,0.f,0.f,0.f}; }

  for (int kc = 0; kc < 8; ++kc){
    bf16x8 an = *(bf16x8*)(&Anew[l15][kc*32 + l4*8]);
    bf16x8 ao = *(bf16x8*)(&Aold[l15][kc*32 + l4*8]);
    #pragma unroll
    for (int nt = 0; nt < 12; ++nt){
      int n = wid*192 + nt*16 + l15;
      bf16x8 bi = *(const bf16x8*)(wihbf + (size_t)n*H + kc*32 + l4*8);
      bf16x8 bh = *(const bf16x8*)(whhbf + (size_t)n*H + kc*32 + l4*8);
      ai[nt] = __builtin_amdgcn_mfma_f32_16x16x32_bf16(an, bi, ai[nt], 0, 0, 0);
      ah[nt] = __builtin_amdgcn_mfma_f32_16x16x32_bf16(ao, bh, ah[nt], 0, 0, 0);
    }
  }

  #pragma unroll
  for (int nt = 0; nt < 12; ++nt){
    int n = wid*192 + nt*16 + l15;
    float bi = bih[n], bh = bhh[n];
    #pragma unroll
    for (int r = 0; r < 4; ++r){
      int row = l4*4 + r;
      float si = ai[nt][r] + bi;
      float sh = ah[nt][r] + bh;
      if (n < 2*H) srz[row][n] = si + sh;
      else { sni[row][n - 2*H] = si; snh[row][n - 2*H] = sh; }
    }
  }
  __syncthreads();

  for (int u = t; u < 16*H; u += 256){
    int row = u >> 8, c = u & 255;
    float rr = sigmoidf_(srz[row][c]);
    float zz = sigmoidf_(srz[row][H + c]);
    float nn = tanhf(sni[row][c] + rr * snh[row][c]);
    float hv = (1.f - zz) * nn + zz * hold[row][c];
    repr_out[(size_t)(g0 + row)*H + c] = fmaxf(hv, 0.f);
  }
}

extern "C" void kernel_launch(void* const* d_in, const int* in_sizes, int n_in,
                              void* d_out, int out_size, void* d_ws, size_t ws_size,
                              hipStream_t stream){
  const float* x    = (const float*)d_in[0];
  const float* w1   = (const float*)d_in[1];
  const float* b1   = (const float*)d_in[2];
  const float* w2   = (const float*)d_in[3];
  const float* b2   = (const float*)d_in[4];
  const float* wih  = (const float*)d_in[5];
  const float* whh  = (const float*)d_in[6];
  const float* bih  = (const float*)d_in[7];
  const float* bhh  = (const float*)d_in[8];
  const int*   batch= (const int*)d_in[9];
  const int N = in_sizes[9];

  char* ws = (char*)d_ws;
  short* w1bf   = (short*)(ws + 0);            // 128 KB
  short* wihbf  = (short*)(ws + (1u<<17));     // 384 KB @128K
  short* whhbf  = (short*)(ws + (1u<<19));     // 384 KB @512K
  float* counts = (float*)(ws + 917504);       // 16 KB
  float* gatesum= (float*)(ws + 933888);       // 16 KB
  float* pool   = (float*)(ws + (1u<<20));     // 4 MB @1M
  float* repr0  = (float*)(ws + (1u<<20) + (1u<<22)); // 4 MB @5M
  float* repr1  = (float*)d_out;               // reuse d_out as repr after t=0
  float* outp   = (float*)d_out;

  const int nblk = (N + TILE - 1) / TILE;

  conv_w<<<768, 256, 0, stream>>>(w1, wih, whh, w1bf, wihbf, whhbf);

  hipMemsetAsync(counts, 0, G*sizeof(float), stream);
  hipMemsetAsync(pool, 0, (size_t)G*H*sizeof(float), stream);
  k0_pool<<<nblk, 256, 0, stream>>>(x, batch, pool, counts, N);
  k0b_div<<<G*H/256, 256, 0, stream>>>(pool, counts, repr0);

  // timestep 0
  hipMemsetAsync(pool, 0, (size_t)G*H*sizeof(float), stream);
  hipMemsetAsync(gatesum, 0, G*sizeof(float), stream);
  k1_gate<<<nblk, 256, 0, stream>>>(x, batch, repr0, w1bf, b1, w2, b2, pool, gatesum, N);
  k2_gru<<<G/16, 256, 0, stream>>>(pool, gatesum, counts, repr0, wihbf, whhbf, bih, bhh, repr1);

  // timestep 1
  hipMemsetAsync(pool, 0, (size_t)G*H*sizeof(float), stream);
  hipMemsetAsync(gatesum, 0, G*sizeof(float), stream);
  k1_gate<<<nblk, 256, 0, stream>>>(x, batch, repr1, w1bf, b1, w2, b2, pool, gatesum, N);
  k2_gru<<<G/16, 256, 0, stream>>>(pool, gatesum, counts, repr1, wihbf, whhbf, bih, bhh, outp);
}

// Round 2
// 1318.490 us; speedup vs baseline: 1.1253x; 1.1253x over previous
//
#include <hip/hip_runtime.h>
#include <hip/hip_bf16.h>
#include <stdint.h>

#define H 256
#define G 4096
#define TILE 64

typedef __attribute__((ext_vector_type(8))) short bf16x8;
typedef __attribute__((ext_vector_type(4))) float f32x4;

__device__ inline short f2bf(float f){
  union { float f; uint32_t u; } v; v.f = f;
  uint32_t r = (v.u + 0x7FFFu + ((v.u >> 16) & 1u)) >> 16;
  return (short)(uint16_t)r;
}
__device__ inline float bf2f(short s){
  union { float f; uint32_t u; } v; v.u = ((uint32_t)(uint16_t)s) << 16;
  return v.f;
}
__device__ inline float sigmoidf_(float x){ return 1.f / (1.f + __expf(-x)); }

// ---------------- weight conversion f32 -> bf16 ----------------
__global__ void conv_w(const float* __restrict__ w1, const float* __restrict__ wih,
                       const float* __restrict__ whh,
                       short* __restrict__ o1, short* __restrict__ oih, short* __restrict__ ohh){
  int i = blockIdx.x * 256 + threadIdx.x;
  if (i < H*H) o1[i] = f2bf(w1[i]);
  if (i < 3*H*H){ oih[i] = f2bf(wih[i]); ohh[i] = f2bf(whh[i]); }
}

// ---------------- K0: initial mean-pool sums + counts ----------------
__global__ __launch_bounds__(1024) void k0_pool(const float* __restrict__ x, const int* __restrict__ batch,
                                                float* __restrict__ pool, float* __restrict__ counts, int nNodes){
  __shared__ int   ng[TILE];
  __shared__ float Pacc[8][H];
  __shared__ float Cacc[8];
  __shared__ int   spanSh;

  const int t = threadIdx.x;
  const int base = blockIdx.x * TILE;

  if (t < TILE) ng[t] = (base + t < nNodes) ? batch[base + t] : -1;
  for (int u = t; u < 8*H; u += 1024) ((float*)Pacc)[u] = 0.f;
  if (t < 8) Cacc[t] = 0.f;
  __syncthreads();

  if (t == 64){
    int lg = -1;
    for (int i = 0; i < TILE; ++i){ int g = ng[i]; if (g >= 0) lg = g; }
    spanSh = (ng[0] >= 0) ? (lg - ng[0]) : -1;
  }

  const int c4 = (t & 63) * 4;
  const int rg = t >> 6;        // 16 row-groups of 4 rows
  const int r0 = rg * 4;

  float4 v[4];
  #pragma unroll
  for (int i = 0; i < 4; ++i){
    int node = base + r0 + i;
    if (node < nNodes) v[i] = *(const float4*)(x + (size_t)node*H + c4);
    else v[i] = make_float4(0.f,0.f,0.f,0.f);
  }
  __syncthreads();

  const int g0 = ng[0];
  const bool useLds = (spanSh >= 0) && (spanSh < 8);

  float ax=0.f, ay=0.f, az=0.f, aw=0.f;
  int cur = ng[r0];
  if (cur >= 0){
    #pragma unroll
    for (int i = 0; i < 4; ++i){
      int g = ng[r0 + i];
      if (g < 0) break;
      if (g != cur){
        if (useLds){
          atomicAdd(&Pacc[cur-g0][c4], ax);   atomicAdd(&Pacc[cur-g0][c4+1], ay);
          atomicAdd(&Pacc[cur-g0][c4+2], az); atomicAdd(&Pacc[cur-g0][c4+3], aw);
        } else {
          atomicAdd(&pool[(size_t)cur*H + c4], ax);   atomicAdd(&pool[(size_t)cur*H + c4+1], ay);
          atomicAdd(&pool[(size_t)cur*H + c4+2], az); atomicAdd(&pool[(size_t)cur*H + c4+3], aw);
        }
        ax=ay=az=aw=0.f; cur = g;
      }
      ax += v[i].x; ay += v[i].y; az += v[i].z; aw += v[i].w;
    }
    if (useLds){
      atomicAdd(&Pacc[cur-g0][c4], ax);   atomicAdd(&Pacc[cur-g0][c4+1], ay);
      atomicAdd(&Pacc[cur-g0][c4+2], az); atomicAdd(&Pacc[cur-g0][c4+3], aw);
    } else {
      atomicAdd(&pool[(size_t)cur*H + c4], ax);   atomicAdd(&pool[(size_t)cur*H + c4+1], ay);
      atomicAdd(&pool[(size_t)cur*H + c4+2], az); atomicAdd(&pool[(size_t)cur*H + c4+3], aw);
    }
  }
  if (t < TILE && ng[t] >= 0){
    if (useLds) atomicAdd(&Cacc[ng[t]-g0], 1.f);
    else        atomicAdd(&counts[ng[t]], 1.f);
  }
  __syncthreads();

  if (useLds){
    int nr = spanSh + 1;
    for (int u = t; u < nr*H; u += 1024){
      int r = u >> 8, c = u & 255;
      float vv = Pacc[r][c];
      if (vv != 0.f) atomicAdd(&pool[(size_t)(g0+r)*H + c], vv);
    }
    if (t < nr && Cacc[t] != 0.f) atomicAdd(&counts[g0 + t], Cacc[t]);
  }
}

// ---------------- K0b: repr = pool / max(counts,1) ----------------
__global__ void k0b_div(const float* __restrict__ pool, const float* __restrict__ counts,
                        float* __restrict__ repr){
  size_t i = (size_t)blockIdx.x * 256 + threadIdx.x;
  int g = (int)(i >> 8);
  repr[i] = pool[i] / fmaxf(counts[g], 1.f);
}

// ---------------- K1: fused gate MLP + weighted pooling ----------------
// pool += sum_i gate_i * bf16(x_i + r_g);  gatesum[g] += gate_i
// (correction  new_repr = (pool - gatesum*r)/cnt  applied in K2)
__global__ __launch_bounds__(1024, 4) void k1_gate(const float* __restrict__ x, const int* __restrict__ batch,
    const float* __restrict__ repr, const short* __restrict__ w1bf,
    const float* __restrict__ b1, const float* __restrict__ w2, const float* __restrict__ b2p,
    float* __restrict__ pool, float* __restrict__ gatesum, int nNodes){

  __shared__ short Ain[TILE][H + 8];      // 33792 B, padded rows
  __shared__ float partials[16][TILE];    // 4096 B
  __shared__ float gates[TILE];
  __shared__ int   ng[TILE];
  __shared__ float Pacc[8][H];            // 8192 B
  __shared__ float Gacc[8];
  __shared__ int   spanSh;

  const int t    = threadIdx.x;
  const int wid  = t >> 6;      // 0..15 : col-tile of 16
  const int lane = t & 63;
  const int l15  = lane & 15;
  const int l4   = lane >> 4;
  const int base = blockIdx.x * TILE;
  const float b2v = b2p[0];

  if (t < TILE) ng[t] = (base + t < nNodes) ? batch[base + t] : -1;
  for (int u = t; u < 8*H; u += 1024) ((float*)Pacc)[u] = 0.f;
  if (t < 8) Gacc[t] = 0.f;

  // W1 slice for this wave's 16 output cols, held in registers (L2-hot)
  bf16x8 Bf[8];
  {
    const short* wp = w1bf + (size_t)(wid*16 + l15)*H + l4*8;
    #pragma unroll
    for (int kc = 0; kc < 8; ++kc) Bf[kc] = *(const bf16x8*)(wp + kc*32);
  }
  const float b1v = b1[wid*16 + l15];
  const float w2v = w2[wid*16 + l15];

  __syncthreads();   // ng + zeros ready

  if (t == 64){
    int lg = -1;
    for (int i = 0; i < TILE; ++i){ int g = ng[i]; if (g >= 0) lg = g; }
    spanSh = (ng[0] >= 0) ? (lg - ng[0]) : -1;
  }

  // stage g_in = bf16(x + repr[batch])
  #pragma unroll
  for (int u = t; u < TILE*32; u += 1024){
    int row = u >> 5, cg = u & 31;
    int c0 = cg * 8;
    int node = base + row;
    bf16x8 o;
    if (node < nNodes){
      int g = ng[row];
      const float4* xp = (const float4*)(x + (size_t)node*H + c0);
      const float4* rp = (const float4*)(repr + (size_t)g*H + c0);
      float4 x0 = xp[0], x1 = xp[1];
      float4 r0 = rp[0], r1 = rp[1];
      o[0]=f2bf(x0.x+r0.x); o[1]=f2bf(x0.y+r0.y); o[2]=f2bf(x0.z+r0.z); o[3]=f2bf(x0.w+r0.w);
      o[4]=f2bf(x1.x+r1.x); o[5]=f2bf(x1.y+r1.y); o[6]=f2bf(x1.z+r1.z); o[7]=f2bf(x1.w+r1.w);
    } else {
      o = (bf16x8)0;
    }
    *(bf16x8*)(&Ain[row][c0]) = o;
  }
  __syncthreads();

  // MFMA: h[0:64][wid*16 : wid*16+16]
  f32x4 acc[4];
  #pragma unroll
  for (int r = 0; r < 4; ++r) acc[r] = (f32x4){0.f,0.f,0.f,0.f};
  #pragma unroll
  for (int kc = 0; kc < 8; ++kc){
    #pragma unroll
    for (int r = 0; r < 4; ++r){
      bf16x8 a = *(bf16x8*)(&Ain[r*16 + l15][kc*32 + l4*8]);
      acc[r] = __builtin_amdgcn_mfma_f32_16x16x32_bf16(a, Bf[kc], acc[r], 0, 0, 0);
    }
  }

  // epilogue: partial w2·relu(h+b1) over this wave's 16 cols
  float p[4][4];
  #pragma unroll
  for (int r = 0; r < 4; ++r)
    #pragma unroll
    for (int j = 0; j < 4; ++j){
      float h = fmaxf(acc[r][j] + b1v, 0.f);
      p[r][j] = w2v * h;
    }
  #pragma unroll
  for (int off = 1; off < 16; off <<= 1){
    #pragma unroll
    for (int r = 0; r < 4; ++r)
      #pragma unroll
      for (int j = 0; j < 4; ++j) p[r][j] += __shfl_xor(p[r][j], off);
  }
  if (l15 == 0){
    #pragma unroll
    for (int r = 0; r < 4; ++r)
      #pragma unroll
      for (int j = 0; j < 4; ++j) partials[wid][r*16 + l4*4 + j] = p[r][j];
  }
  __syncthreads();

  if (t < TILE){
    float s = b2v;
    #pragma unroll
    for (int w = 0; w < 16; ++w) s += partials[w][t];
    int node = base + t;
    gates[t] = (node < nNodes) ? sigmoidf_(s) : 0.f;
  }
  __syncthreads();

  // weighted pooling: 8 row-groups x 128 col-pairs, register run-length,
  // flush to LDS Pacc (graph-id span < 8) then one global atomic per slot.
  const int g0 = ng[0];
  const bool useLds = (spanSh >= 0) && (spanSh < 8);
  {
    const int c2 = (t & 127) * 2;
    const int rg = t >> 7;      // 0..7 : 8 rows each
    const int r0 = rg * 8;

    uint32_t av[8]; float gv[8];
    #pragma unroll
    for (int i = 0; i < 8; ++i){
      av[i] = *(const uint32_t*)(&Ain[r0 + i][c2]);
      gv[i] = gates[r0 + i];
    }

    float ax = 0.f, ay = 0.f;
    int cur = ng[r0];
    if (cur >= 0){
      #pragma unroll
      for (int i = 0; i < 8; ++i){
        int g = ng[r0 + i];
        if (g < 0) break;
        if (g != cur){
          if (useLds){ atomicAdd(&Pacc[cur-g0][c2], ax); atomicAdd(&Pacc[cur-g0][c2+1], ay); }
          else { atomicAdd(&pool[(size_t)cur*H + c2], ax); atomicAdd(&pool[(size_t)cur*H + c2+1], ay); }
          ax = ay = 0.f; cur = g;
        }
        float lo = bf2f((short)(uint16_t)(av[i] & 0xFFFFu));
        float hi = bf2f((short)(uint16_t)(av[i] >> 16));
        ax += gv[i] * lo; ay += gv[i] * hi;
      }
      if (useLds){ atomicAdd(&Pacc[cur-g0][c2], ax); atomicAdd(&Pacc[cur-g0][c2+1], ay); }
      else { atomicAdd(&pool[(size_t)cur*H + c2], ax); atomicAdd(&pool[(size_t)cur*H + c2+1], ay); }
    }
    // gatesum per row-group
    if ((t & 127) == 0 && ng[r0] >= 0){
      float gs = 0.f; int cg = ng[r0];
      #pragma unroll
      for (int i = 0; i < 8; ++i){
        int g = ng[r0 + i];
        if (g < 0) break;
        if (g != cg){
          if (useLds) atomicAdd(&Gacc[cg - g0], gs); else atomicAdd(&gatesum[cg], gs);
          gs = 0.f; cg = g;
        }
        gs += gv[i];
      }
      if (useLds) atomicAdd(&Gacc[cg - g0], gs); else atomicAdd(&gatesum[cg], gs);
    }
  }
  __syncthreads();

  if (useLds){
    int nr = spanSh + 1;
    for (int u = t; u < nr*H; u += 1024){
      int r = u >> 8, c = u & 255;
      float vv = Pacc[r][c];
      if (vv != 0.f) atomicAdd(&pool[(size_t)(g0+r)*H + c], vv);
    }
    if (t < nr && Gacc[t] != 0.f) atomicAdd(&gatesum[g0 + t], Gacc[t]);
  }
}

// ---------------- K2: fused GRU over 16 graphs/block ----------------
__global__ __launch_bounds__(256) void k2_gru(const float* __restrict__ pool, const float* __restrict__ gatesum,
    const float* __restrict__ counts, const float* __restrict__ repr_in,
    const short* __restrict__ wihbf, const short* __restrict__ whhbf,
    const float* __restrict__ bih, const float* __restrict__ bhh,
    float* __restrict__ repr_out){

  __shared__ short Anew[16][H + 8];
  __shared__ short Aold[16][H + 8];
  __shared__ float hold[16][H];
  __shared__ float srz[16][2*H];
  __shared__ float sni[16][H];
  __shared__ float snh[16][H];

  const int t    = threadIdx.x;
  const int wid  = t >> 6;
  const int lane = t & 63;
  const int l15  = lane & 15;
  const int l4   = lane >> 4;
  const int g0   = blockIdx.x * 16;

  for (int u = t; u < 16*H; u += 256){
    int row = u >> 8, c = u & 255;
    int g = g0 + row;
    float cnt = fmaxf(counts[g], 1.f);
    float rin = repr_in[(size_t)g*H + c];
    float nr  = (pool[(size_t)g*H + c] - gatesum[g]*rin) / cnt;
    Anew[row][c] = f2bf(nr);
    Aold[row][c] = f2bf(rin);
    hold[row][c] = rin;
  }
  __syncthreads();

  f32x4 ai[12], ah[12];
  #pragma unroll
  for (int i = 0; i < 12; ++i){ ai[i] = (f32x4){0.f,0.f,0.f,0.f}; ah[i] = (f32x4){0.f,0.f,0.f,0.f}; }

  for (int kc = 0; kc < 8; ++kc){
    bf16x8 an = *(bf16x8*)(&Anew[l15][kc*32 + l4*8]);
    bf16x8 ao = *(bf16x8*)(&Aold[l15][kc*32 + l4*8]);
    #pragma unroll
    for (int nt = 0; nt < 12; ++nt){
      int n = wid*192 + nt*16 + l15;
      bf16x8 bi = *(const bf16x8*)(wihbf + (size_t)n*H + kc*32 + l4*8);
      bf16x8 bh = *(const bf16x8*)(whhbf + (size_t)n*H + kc*32 + l4*8);
      ai[nt] = __builtin_amdgcn_mfma_f32_16x16x32_bf16(an, bi, ai[nt], 0, 0, 0);
      ah[nt] = __builtin_amdgcn_mfma_f32_16x16x32_bf16(ao, bh, ah[nt], 0, 0, 0);
    }
  }

  #pragma unroll
  for (int nt = 0; nt < 12; ++nt){
    int n = wid*192 + nt*16 + l15;
    float bi = bih[n], bh = bhh[n];
    #pragma unroll
    for (int r = 0; r < 4; ++r){
      int row = l4*4 + r;
      float si = ai[nt][r] + bi;
      float sh = ah[nt][r] + bh;
      if (n < 2*H) srz[row][n] = si + sh;
      else { sni[row][n - 2*H] = si; snh[row][n - 2*H] = sh; }
    }
  }
  __syncthreads();

  for (int u = t; u < 16*H; u += 256){
    int row = u >> 8, c = u & 255;
    float rr = sigmoidf_(srz[row][c]);
    float zz = sigmoidf_(srz[row][H + c]);
    float nn = tanhf(sni[row][c] + rr * snh[row][c]);
    float hv = (1.f - zz) * nn + zz * hold[row][c];
    repr_out[(size_t)(g0 + row)*H + c] = fmaxf(hv, 0.f);
  }
}

extern "C" void kernel_launch(void* const* d_in, const int* in_sizes, int n_in,
                              void* d_out, int out_size, void* d_ws, size_t ws_size,
                              hipStream_t stream){
  const float* x    = (const float*)d_in[0];
  const float* w1   = (const float*)d_in[1];
  const float* b1   = (const float*)d_in[2];
  const float* w2   = (const float*)d_in[3];
  const float* b2   = (const float*)d_in[4];
  const float* wih  = (const float*)d_in[5];
  const float* whh  = (const float*)d_in[6];
  const float* bih  = (const float*)d_in[7];
  const float* bhh  = (const float*)d_in[8];
  const int*   batch= (const int*)d_in[9];
  const int N = in_sizes[9];

  char* ws = (char*)d_ws;
  short* w1bf   = (short*)(ws + 0);            // 128 KB
  short* wihbf  = (short*)(ws + (1u<<17));     // 384 KB @128K
  short* whhbf  = (short*)(ws + (1u<<19));     // 384 KB @512K
  float* counts = (float*)(ws + 917504);       // 16 KB
  float* gatesum= (float*)(ws + 933888);       // 16 KB
  float* pool   = (float*)(ws + (1u<<20));     // 4 MB @1M
  float* repr0  = (float*)(ws + (1u<<20) + (1u<<22)); // 4 MB @5M
  float* repr1  = (float*)d_out;               // reuse d_out as repr after t=0
  float* outp   = (float*)d_out;

  const int nblk = (N + TILE - 1) / TILE;

  conv_w<<<768, 256, 0, stream>>>(w1, wih, whh, w1bf, wihbf, whhbf);

  hipMemsetAsync(counts, 0, G*sizeof(float), stream);
  hipMemsetAsync(pool, 0, (size_t)G*H*sizeof(float), stream);
  k0_pool<<<nblk, 1024, 0, stream>>>(x, batch, pool, counts, N);
  k0b_div<<<G*H/256, 256, 0, stream>>>(pool, counts, repr0);

  // timestep 0
  hipMemsetAsync(pool, 0, (size_t)G*H*sizeof(float), stream);
  hipMemsetAsync(gatesum, 0, G*sizeof(float), stream);
  k1_gate<<<nblk, 1024, 0, stream>>>(x, batch, repr0, w1bf, b1, w2, b2, pool, gatesum, N);
  k2_gru<<<G/16, 256, 0, stream>>>(pool, gatesum, counts, repr0, wihbf, whhbf, bih, bhh, repr1);

  // timestep 1
  hipMemsetAsync(pool, 0, (size_t)G*H*sizeof(float), stream);
  hipMemsetAsync(gatesum, 0, G*sizeof(float), stream);
  k1_gate<<<nblk, 1024, 0, stream>>>(x, batch, repr1, w1bf, b1, w2, b2, pool, gatesum, N);
  k2_gru<<<G/16, 256, 0, stream>>>(pool, gatesum, counts, repr1, wihbf, whhbf, bih, bhh, outp);
}

// Round 3
// 1147.518 us; speedup vs baseline: 1.2930x; 1.1490x over previous
//
#include <hip/hip_runtime.h>
#include <hip/hip_bf16.h>
#include <stdint.h>

#define H 256
#define G 4096
#define TK 32

typedef __attribute__((ext_vector_type(8))) short bf16x8;
typedef __attribute__((ext_vector_type(4))) float f32x4;

__device__ inline short f2bf(float f){
  union { float f; uint32_t u; } v; v.f = f;
  uint32_t r = (v.u + 0x7FFFu + ((v.u >> 16) & 1u)) >> 16;
  return (short)(uint16_t)r;
}
__device__ inline float bf2f(short s){
  union { float f; uint32_t u; } v; v.u = ((uint32_t)(uint16_t)s) << 16;
  return v.f;
}
__device__ inline float sigmoidf_(float x){ return 1.f / (1.f + __expf(-x)); }

// ---------------- weight conversion f32 -> bf16 ----------------
__global__ void conv_w(const float* __restrict__ w1, const float* __restrict__ wih,
                       const float* __restrict__ whh,
                       short* __restrict__ o1, short* __restrict__ oih, short* __restrict__ ohh){
  int i = blockIdx.x * 256 + threadIdx.x;
  if (i < H*H) o1[i] = f2bf(w1[i]);
  if (i < 3*H*H){ oih[i] = f2bf(wih[i]); ohh[i] = f2bf(whh[i]); }
}

// ---------------- K0: initial mean-pool sums + counts (32-node tiles) ----------------
__global__ __launch_bounds__(256) void k0_pool(const float* __restrict__ x, const int* __restrict__ batch,
                                               float* __restrict__ pool, float* __restrict__ counts, int nNodes){
  __shared__ int   ng[TK];
  __shared__ float Pacc[8][H];
  __shared__ float Cacc[8];
  __shared__ int   spanSh;

  const int t = threadIdx.x;
  const int base = blockIdx.x * TK;

  if (t < TK) ng[t] = (base + t < nNodes) ? batch[base + t] : -1;
  for (int u = t; u < 8*H; u += 256) ((float*)Pacc)[u] = 0.f;
  if (t < 8) Cacc[t] = 0.f;
  __syncthreads();

  if (t == 64){
    int lg = ng[0];
    for (int i = 1; i < TK; ++i){ int g = ng[i]; if (g >= 0) lg = g; }
    spanSh = (ng[0] >= 0) ? (lg - ng[0]) : -1;
  }

  const int c4 = (t & 63) * 4;
  const int rg = t >> 6;        // 4 row-groups of 8 rows
  const int r0 = rg * 8;

  float4 v[8];
  #pragma unroll
  for (int i = 0; i < 8; ++i){
    int node = base + r0 + i;
    if (node < nNodes) v[i] = *(const float4*)(x + (size_t)node*H + c4);
    else v[i] = make_float4(0.f,0.f,0.f,0.f);
  }
  __syncthreads();

  const int g0 = ng[0];
  const bool useLds = (spanSh >= 0) && (spanSh < 8);

  float ax=0.f, ay=0.f, az=0.f, aw=0.f;
  int cur = ng[r0];
  if (cur >= 0){
    #pragma unroll
    for (int i = 0; i < 8; ++i){
      int g = ng[r0 + i];
      if (g < 0) break;
      if (g != cur){
        if (useLds){
          atomicAdd(&Pacc[cur-g0][c4], ax);   atomicAdd(&Pacc[cur-g0][c4+1], ay);
          atomicAdd(&Pacc[cur-g0][c4+2], az); atomicAdd(&Pacc[cur-g0][c4+3], aw);
        } else {
          atomicAdd(&pool[(size_t)cur*H + c4], ax);   atomicAdd(&pool[(size_t)cur*H + c4+1], ay);
          atomicAdd(&pool[(size_t)cur*H + c4+2], az); atomicAdd(&pool[(size_t)cur*H + c4+3], aw);
        }
        ax=ay=az=aw=0.f; cur = g;
      }
      ax += v[i].x; ay += v[i].y; az += v[i].z; aw += v[i].w;
    }
    if (useLds){
      atomicAdd(&Pacc[cur-g0][c4], ax);   atomicAdd(&Pacc[cur-g0][c4+1], ay);
      atomicAdd(&Pacc[cur-g0][c4+2], az); atomicAdd(&Pacc[cur-g0][c4+3], aw);
    } else {
      atomicAdd(&pool[(size_t)cur*H + c4], ax);   atomicAdd(&pool[(size_t)cur*H + c4+1], ay);
      atomicAdd(&pool[(size_t)cur*H + c4+2], az); atomicAdd(&pool[(size_t)cur*H + c4+3], aw);
    }
  }
  if (t < TK && ng[t] >= 0){
    if (useLds) atomicAdd(&Cacc[ng[t]-g0], 1.f);
    else        atomicAdd(&counts[ng[t]], 1.f);
  }
  __syncthreads();

  if (useLds){
    int nr = spanSh + 1;
    for (int u = t; u < nr*H; u += 256){
      int r = u >> 8, c = u & 255;
      float vv = Pacc[r][c];
      if (vv != 0.f) atomicAdd(&pool[(size_t)(g0+r)*H + c], vv);
    }
    if (t < nr && Cacc[t] != 0.f) atomicAdd(&counts[g0 + t], Cacc[t]);
  }
}

// ---------------- K0b: repr = pool / max(counts,1) ----------------
__global__ void k0b_div(const float* __restrict__ pool, const float* __restrict__ counts,
                        float* __restrict__ repr){
  size_t i = (size_t)blockIdx.x * 256 + threadIdx.x;
  int g = (int)(i >> 8);
  repr[i] = pool[i] / fmaxf(counts[g], 1.f);
}

// ---------------- KT: hg[g] = W1 * bf16(repr[g]) + b1 ----------------
__global__ __launch_bounds__(256) void kT_hg(const float* __restrict__ repr,
    const short* __restrict__ w1bf, const float* __restrict__ b1,
    float* __restrict__ hg){
  __shared__ short Ar[16][H + 8];
  const int t    = threadIdx.x;
  const int wid  = t >> 6;
  const int lane = t & 63;
  const int l15  = lane & 15;
  const int l4   = lane >> 4;
  const int g0   = blockIdx.x * 16;

  for (int u = t; u < 16*32; u += 256){
    int row = u >> 5, cg = u & 31;
    int c0 = cg * 8;
    const float4* rp = (const float4*)(repr + (size_t)(g0+row)*H + c0);
    float4 r0 = rp[0], r1 = rp[1];
    bf16x8 o;
    o[0]=f2bf(r0.x); o[1]=f2bf(r0.y); o[2]=f2bf(r0.z); o[3]=f2bf(r0.w);
    o[4]=f2bf(r1.x); o[5]=f2bf(r1.y); o[6]=f2bf(r1.z); o[7]=f2bf(r1.w);
    *(bf16x8*)(&Ar[row][c0]) = o;
  }
  __syncthreads();

  f32x4 acc[4];
  #pragma unroll
  for (int i = 0; i < 4; ++i) acc[i] = (f32x4){0.f,0.f,0.f,0.f};
  #pragma unroll
  for (int kc = 0; kc < 8; ++kc){
    bf16x8 a = *(bf16x8*)(&Ar[l15][kc*32 + l4*8]);
    #pragma unroll
    for (int nt = 0; nt < 4; ++nt){
      int col = wid*64 + nt*16 + l15;
      bf16x8 b = *(const bf16x8*)(w1bf + (size_t)col*H + kc*32 + l4*8);
      acc[nt] = __builtin_amdgcn_mfma_f32_16x16x32_bf16(a, b, acc[nt], 0, 0, 0);
    }
  }
  #pragma unroll
  for (int nt = 0; nt < 4; ++nt){
    int col = wid*64 + nt*16 + l15;
    float b1v = b1[col];
    #pragma unroll
    for (int j = 0; j < 4; ++j){
      int row = l4*4 + j;
      hg[(size_t)(g0+row)*H + col] = acc[nt][j] + b1v;
    }
  }
}

// ---------------- K1: fused gate MLP + weighted pooling (32-node tiles, 512 thr) ----------------
// h = relu(W1*bf16(x) + hg[g]); gate = sigmoid(w2.h + b2); pool[g] += gate * bf16(x)
__global__ __launch_bounds__(512, 4) void k1_gate(const float* __restrict__ x,
    const int* __restrict__ batch, const float* __restrict__ hg,
    const short* __restrict__ w1bf, const float* __restrict__ w2,
    const float* __restrict__ b2p, float* __restrict__ pool, int nNodes){

  __shared__ short Ain[TK][H + 8];        // 16.9 KB
  __shared__ float Pacc[8][H];            // 8 KB
  __shared__ float partials[8][TK];       // 1 KB
  __shared__ float gates[TK];
  __shared__ int   ng[TK];
  __shared__ int   spanSh;

  const int t    = threadIdx.x;
  const int wid  = t >> 6;      // 0..7 : col-block of 32
  const int lane = t & 63;
  const int l15  = lane & 15;
  const int l4   = lane >> 4;
  const int base = blockIdx.x * TK;
  const float b2v = b2p[0];

  if (t < TK) ng[t] = (base + t < nNodes) ? batch[base + t] : -1;
  for (int u = t; u < 8*H; u += 512) ((float*)Pacc)[u] = 0.f;

  // W1 slices for this wave's 32 output cols (two 16-col tiles), in registers
  bf16x8 Bf0[8], Bf1[8];
  {
    const short* wp0 = w1bf + (size_t)(wid*32 + l15)*H + l4*8;
    const short* wp1 = wp0 + 16*H;
    #pragma unroll
    for (int kc = 0; kc < 8; ++kc){
      Bf0[kc] = *(const bf16x8*)(wp0 + kc*32);
      Bf1[kc] = *(const bf16x8*)(wp1 + kc*32);
    }
  }
  const float w2v0 = w2[wid*32 + l15];
  const float w2v1 = w2[wid*32 + 16 + l15];

  __syncthreads();
  if (t == 64){
    int lg = ng[0];
    for (int i = 1; i < TK; ++i){ int g = ng[i]; if (g >= 0) lg = g; }
    spanSh = (ng[0] >= 0) ? (lg - ng[0]) : -1;
  }

  // stage bf16(x) tile
  #pragma unroll
  for (int u = t; u < TK*32; u += 512){
    int row = u >> 5, cg = u & 31;
    int c0 = cg * 8;
    int node = base + row;
    bf16x8 o;
    if (node < nNodes){
      const float4* xp = (const float4*)(x + (size_t)node*H + c0);
      float4 x0 = xp[0], x1 = xp[1];
      o[0]=f2bf(x0.x); o[1]=f2bf(x0.y); o[2]=f2bf(x0.z); o[3]=f2bf(x0.w);
      o[4]=f2bf(x1.x); o[5]=f2bf(x1.y); o[6]=f2bf(x1.z); o[7]=f2bf(x1.w);
    } else {
      o = (bf16x8)0;
    }
    *(bf16x8*)(&Ain[row][c0]) = o;
  }
  __syncthreads();

  // MFMA: rows 0..31, cols wid*32..wid*32+32
  f32x4 acc0[2], acc1[2];
  #pragma unroll
  for (int r = 0; r < 2; ++r){ acc0[r] = (f32x4){0.f,0.f,0.f,0.f}; acc1[r] = (f32x4){0.f,0.f,0.f,0.f}; }
  #pragma unroll
  for (int kc = 0; kc < 8; ++kc){
    #pragma unroll
    for (int r = 0; r < 2; ++r){
      bf16x8 a = *(bf16x8*)(&Ain[r*16 + l15][kc*32 + l4*8]);
      acc0[r] = __builtin_amdgcn_mfma_f32_16x16x32_bf16(a, Bf0[kc], acc0[r], 0, 0, 0);
      acc1[r] = __builtin_amdgcn_mfma_f32_16x16x32_bf16(a, Bf1[kc], acc1[r], 0, 0, 0);
    }
  }

  // epilogue: p = sum over this wave's 32 cols of w2*relu(acc + hg[g][col])
  float p[2][4];
  #pragma unroll
  for (int r = 0; r < 2; ++r){
    #pragma unroll
    for (int j = 0; j < 4; ++j){
      int row = r*16 + l4*4 + j;
      int g = ng[row];
      float val = 0.f;
      if (g >= 0){
        const float* hgr = hg + (size_t)g*H + wid*32;
        float h0 = fmaxf(acc0[r][j] + hgr[l15], 0.f);
        float h1 = fmaxf(acc1[r][j] + hgr[16 + l15], 0.f);
        val = w2v0*h0 + w2v1*h1;
      }
      p[r][j] = val;
    }
  }
  #pragma unroll
  for (int off = 1; off < 16; off <<= 1){
    #pragma unroll
    for (int r = 0; r < 2; ++r)
      #pragma unroll
      for (int j = 0; j < 4; ++j) p[r][j] += __shfl_xor(p[r][j], off);
  }
  if (l15 == 0){
    #pragma unroll
    for (int r = 0; r < 2; ++r)
      #pragma unroll
      for (int j = 0; j < 4; ++j) partials[wid][r*16 + l4*4 + j] = p[r][j];
  }
  __syncthreads();

  if (t < TK){
    float s = b2v;
    #pragma unroll
    for (int w = 0; w < 8; ++w) s += partials[w][t];
    gates[t] = (base + t < nNodes) ? sigmoidf_(s) : 0.f;
  }
  __syncthreads();

  // weighted pooling: 4 row-groups x 128 col-pairs, register run-length
  const int g0 = ng[0];
  const bool useLds = (spanSh >= 0) && (spanSh < 8);
  {
    const int c2 = (t & 127) * 2;
    const int rg = t >> 7;      // 0..3 : 8 rows each
    const int r0 = rg * 8;

    uint32_t av[8]; float gv[8];
    #pragma unroll
    for (int i = 0; i < 8; ++i){
      av[i] = *(const uint32_t*)(&Ain[r0 + i][c2]);
      gv[i] = gates[r0 + i];
    }

    float ax = 0.f, ay = 0.f;
    int cur = ng[r0];
    if (cur >= 0){
      #pragma unroll
      for (int i = 0; i < 8; ++i){
        int g = ng[r0 + i];
        if (g < 0) break;
        if (g != cur){
          if (useLds){ atomicAdd(&Pacc[cur-g0][c2], ax); atomicAdd(&Pacc[cur-g0][c2+1], ay); }
          else { atomicAdd(&pool[(size_t)cur*H + c2], ax); atomicAdd(&pool[(size_t)cur*H + c2+1], ay); }
          ax = ay = 0.f; cur = g;
        }
        float lo = bf2f((short)(uint16_t)(av[i] & 0xFFFFu));
        float hi = bf2f((short)(uint16_t)(av[i] >> 16));
        ax += gv[i] * lo; ay += gv[i] * hi;
      }
      if (useLds){ atomicAdd(&Pacc[cur-g0][c2], ax); atomicAdd(&Pacc[cur-g0][c2+1], ay); }
      else { atomicAdd(&pool[(size_t)cur*H + c2], ax); atomicAdd(&pool[(size_t)cur*H + c2+1], ay); }
    }
  }
  __syncthreads();

  if (useLds){
    int nr = spanSh + 1;
    for (int u = t; u < nr*H; u += 512){
      int r = u >> 8, c = u & 255;
      float vv = Pacc[r][c];
      if (vv != 0.f) atomicAdd(&pool[(size_t)(g0+r)*H + c], vv);
    }
  }
}

// ---------------- K2: fused GRU over 16 graphs/block ----------------
__global__ __launch_bounds__(256) void k2_gru(const float* __restrict__ pool,
    const float* __restrict__ counts, const float* __restrict__ repr_in,
    const short* __restrict__ wihbf, const short* __restrict__ whhbf,
    const float* __restrict__ bih, const float* __restrict__ bhh,
    float* __restrict__ repr_out){

  __shared__ short Anew[16][H + 8];
  __shared__ short Aold[16][H + 8];
  __shared__ float hold[16][H];
  __shared__ float srz[16][2*H];
  __shared__ float sni[16][H];
  __shared__ float snh[16][H];

  const int t    = threadIdx.x;
  const int wid  = t >> 6;
  const int lane = t & 63;
  const int l15  = lane & 15;
  const int l4   = lane >> 4;
  const int g0   = blockIdx.x * 16;

  for (int u = t; u < 16*H; u += 256){
    int row = u >> 8, c = u & 255;
    int g = g0 + row;
    float cnt = fmaxf(counts[g], 1.f);
    float rin = repr_in[(size_t)g*H + c];
    float nr  = pool[(size_t)g*H + c] / cnt;
    Anew[row][c] = f2bf(nr);
    Aold[row][c] = f2bf(rin);
    hold[row][c] = rin;
  }
  __syncthreads();

  f32x4 ai[12], ah[12];
  #pragma unroll
  for (int i = 0; i < 12; ++i){ ai[i] = (f32x4){0.f,0.f,0.f,0.f}; ah[i] = (f32x4){0.f,0.f,0.f,0.f}; }

  for (int kc = 0; kc < 8; ++kc){
    bf16x8 an = *(bf16x8*)(&Anew[l15][kc*32 + l4*8]);
    bf16x8 ao = *(bf16x8*)(&Aold[l15][kc*32 + l4*8]);
    #pragma unroll
    for (int nt = 0; nt < 12; ++nt){
      int n = wid*192 + nt*16 + l15;
      bf16x8 bi = *(const bf16x8*)(wihbf + (size_t)n*H + kc*32 + l4*8);
      bf16x8 bh = *(const bf16x8*)(whhbf + (size_t)n*H + kc*32 + l4*8);
      ai[nt] = __builtin_amdgcn_mfma_f32_16x16x32_bf16(an, bi, ai[nt], 0, 0, 0);
      ah[nt] = __builtin_amdgcn_mfma_f32_16x16x32_bf16(ao, bh, ah[nt], 0, 0, 0);
    }
  }

  #pragma unroll
  for (int nt = 0; nt < 12; ++nt){
    int n = wid*192 + nt*16 + l15;
    float bi = bih[n], bh = bhh[n];
    #pragma unroll
    for (int r = 0; r < 4; ++r){
      int row = l4*4 + r;
      float si = ai[nt][r] + bi;
      float sh = ah[nt][r] + bh;
      if (n < 2*H) srz[row][n] = si + sh;
      else { sni[row][n - 2*H] = si; snh[row][n - 2*H] = sh; }
    }
  }
  __syncthreads();

  for (int u = t; u < 16*H; u += 256){
    int row = u >> 8, c = u & 255;
    float rr = sigmoidf_(srz[row][c]);
    float zz = sigmoidf_(srz[row][H + c]);
    float nn = tanhf(sni[row][c] + rr * snh[row][c]);
    float hv = (1.f - zz) * nn + zz * hold[row][c];
    repr_out[(size_t)(g0 + row)*H + c] = fmaxf(hv, 0.f);
  }
}

extern "C" void kernel_launch(void* const* d_in, const int* in_sizes, int n_in,
                              void* d_out, int out_size, void* d_ws, size_t ws_size,
                              hipStream_t stream){
  const float* x    = (const float*)d_in[0];
  const float* w1   = (const float*)d_in[1];
  const float* b1   = (const float*)d_in[2];
  const float* w2   = (const float*)d_in[3];
  const float* b2   = (const float*)d_in[4];
  const float* wih  = (const float*)d_in[5];
  const float* whh  = (const float*)d_in[6];
  const float* bih  = (const float*)d_in[7];
  const float* bhh  = (const float*)d_in[8];
  const int*   batch= (const int*)d_in[9];
  const int N = in_sizes[9];

  char* ws = (char*)d_ws;
  short* w1bf   = (short*)(ws + 0);            // 128 KB
  short* wihbf  = (short*)(ws + (1u<<17));     // 384 KB @128K
  short* whhbf  = (short*)(ws + (1u<<19));     // 384 KB @512K
  float* counts = (float*)(ws + 917504);       // 16 KB @896K
  float* pool   = (float*)(ws + (1u<<20));     // 4 MB @1M
  float* repr   = (float*)(ws + (1u<<20) + (1u<<22)); // 4 MB @5M
  float* hg     = (float*)d_out;               // 4 MB, dead before final k2 writes output
  float* outp   = (float*)d_out;

  const int nblk = (N + TK - 1) / TK;          // 15625

  conv_w<<<768, 256, 0, stream>>>(w1, wih, whh, w1bf, wihbf, whhbf);

  hipMemsetAsync(counts, 0, G*sizeof(float), stream);
  hipMemsetAsync(pool, 0, (size_t)G*H*sizeof(float), stream);
  k0_pool<<<nblk, 256, 0, stream>>>(x, batch, pool, counts, N);
  k0b_div<<<G*H/256, 256, 0, stream>>>(pool, counts, repr);

  // timestep 0
  kT_hg<<<G/16, 256, 0, stream>>>(repr, w1bf, b1, hg);
  hipMemsetAsync(pool, 0, (size_t)G*H*sizeof(float), stream);
  k1_gate<<<nblk, 512, 0, stream>>>(x, batch, hg, w1bf, w2, b2, pool, N);
  k2_gru<<<G/16, 256, 0, stream>>>(pool, counts, repr, wihbf, whhbf, bih, bhh, repr); // in-place

  // timestep 1
  kT_hg<<<G/16, 256, 0, stream>>>(repr, w1bf, b1, hg);
  hipMemsetAsync(pool, 0, (size_t)G*H*sizeof(float), stream);
  k1_gate<<<nblk, 512, 0, stream>>>(x, batch, hg, w1bf, w2, b2, pool, N);
  k2_gru<<<G/16, 256, 0, stream>>>(pool, counts, repr, wihbf, whhbf, bih, bhh, outp);
}

// Round 4
// 840.690 us; speedup vs baseline: 1.7649x; 1.3650x over previous
//
#include <hip/hip_runtime.h>
#include <hip/hip_bf16.h>
#include <stdint.h>

#define H 256
#define G 4096
#define TK 32     // k1 tile rows
#define T0 64     // k0 tile rows

typedef __attribute__((ext_vector_type(8))) short bf16x8;
typedef __attribute__((ext_vector_type(4))) float f32x4;

__device__ inline short f2bf(float f){
  union { float f; uint32_t u; } v; v.f = f;
  uint32_t r = (v.u + 0x7FFFu + ((v.u >> 16) & 1u)) >> 16;
  return (short)(uint16_t)r;
}
__device__ inline float bf2f(short s){
  union { float f; uint32_t u; } v; v.u = ((uint32_t)(uint16_t)s) << 16;
  return v.f;
}
__device__ inline float sigmoidf_(float x){ return 1.f / (1.f + __expf(-x)); }

// LDS-only barrier: does NOT drain vmcnt, so prefetched global loads stay in flight.
__device__ inline void ldsbar(){
  asm volatile("s_waitcnt lgkmcnt(0)" ::: "memory");
  __builtin_amdgcn_s_barrier();
}

// ---------------- weight conversion f32 -> bf16 ----------------
__global__ void conv_w(const float* __restrict__ w1, const float* __restrict__ wih,
                       const float* __restrict__ whh,
                       short* __restrict__ o1, short* __restrict__ oih, short* __restrict__ ohh){
  int i = blockIdx.x * 256 + threadIdx.x;
  if (i < H*H) o1[i] = f2bf(w1[i]);
  if (i < 3*H*H){ oih[i] = f2bf(wih[i]); ohh[i] = f2bf(whh[i]); }
}

// ---------------- K0: mean-pool sums + counts + write x_bf16 ----------------
__global__ __launch_bounds__(512) void k0_pool(const float* __restrict__ x, const int* __restrict__ batch,
                                               float* __restrict__ pool, float* __restrict__ counts,
                                               short* __restrict__ xbf, int nNodes){
  __shared__ int   ng[T0];
  __shared__ float Pacc[8][H];
  __shared__ float Cacc[8];
  __shared__ int   spanSh;

  const int t = threadIdx.x;
  const int base = blockIdx.x * T0;

  if (t < T0) ng[t] = (base + t < nNodes) ? batch[base + t] : -1;
  for (int u = t; u < 8*H; u += 512) ((float*)Pacc)[u] = 0.f;
  if (t < 8) Cacc[t] = 0.f;
  __syncthreads();

  if (t == 64){
    int lg = ng[0];
    for (int i = 1; i < T0; ++i){ int g = ng[i]; if (g >= 0) lg = g; }
    spanSh = (ng[0] >= 0) ? (lg - ng[0]) : -1;
  }

  const int c4 = (t & 63) * 4;
  const int rg = t >> 6;        // 8 row-groups of 8 rows
  const int r0 = rg * 8;

  float4 v[8];
  #pragma unroll
  for (int i = 0; i < 8; ++i){
    int node = base + r0 + i;
    if (node < nNodes) v[i] = *(const float4*)(x + (size_t)node*H + c4);
    else v[i] = make_float4(0.f,0.f,0.f,0.f);
  }
  // write bf16 copy of x
  if (xbf){
    #pragma unroll
    for (int i = 0; i < 8; ++i){
      int node = base + r0 + i;
      if (node < nNodes){
        ushort4 o;
        o.x = (uint16_t)f2bf(v[i].x); o.y = (uint16_t)f2bf(v[i].y);
        o.z = (uint16_t)f2bf(v[i].z); o.w = (uint16_t)f2bf(v[i].w);
        *(ushort4*)(xbf + (size_t)node*H + c4) = o;
      }
    }
  }
  __syncthreads();

  const int g0 = ng[0];
  const bool useLds = (spanSh >= 0) && (spanSh < 8);

  float ax=0.f, ay=0.f, az=0.f, aw=0.f;
  int cur = ng[r0];
  if (cur >= 0){
    #pragma unroll
    for (int i = 0; i < 8; ++i){
      int g = ng[r0 + i];
      if (g < 0) break;
      if (g != cur){
        if (useLds){
          atomicAdd(&Pacc[cur-g0][c4], ax);   atomicAdd(&Pacc[cur-g0][c4+1], ay);
          atomicAdd(&Pacc[cur-g0][c4+2], az); atomicAdd(&Pacc[cur-g0][c4+3], aw);
        } else {
          atomicAdd(&pool[(size_t)cur*H + c4], ax);   atomicAdd(&pool[(size_t)cur*H + c4+1], ay);
          atomicAdd(&pool[(size_t)cur*H + c4+2], az); atomicAdd(&pool[(size_t)cur*H + c4+3], aw);
        }
        ax=ay=az=aw=0.f; cur = g;
      }
      ax += v[i].x; ay += v[i].y; az += v[i].z; aw += v[i].w;
    }
    if (useLds){
      atomicAdd(&Pacc[cur-g0][c4], ax);   atomicAdd(&Pacc[cur-g0][c4+1], ay);
      atomicAdd(&Pacc[cur-g0][c4+2], az); atomicAdd(&Pacc[cur-g0][c4+3], aw);
    } else {
      atomicAdd(&pool[(size_t)cur*H + c4], ax);   atomicAdd(&pool[(size_t)cur*H + c4+1], ay);
      atomicAdd(&pool[(size_t)cur*H + c4+2], az); atomicAdd(&pool[(size_t)cur*H + c4+3], aw);
    }
  }
  if (t < T0 && ng[t] >= 0){
    if (useLds) atomicAdd(&Cacc[ng[t]-g0], 1.f);
    else        atomicAdd(&counts[ng[t]], 1.f);
  }
  __syncthreads();

  if (useLds){
    int nr = spanSh + 1;
    for (int u = t; u < nr*H; u += 512){
      int r = u >> 8, c = u & 255;
      float vv = Pacc[r][c];
      if (vv != 0.f) atomicAdd(&pool[(size_t)(g0+r)*H + c], vv);
    }
    if (t < nr && Cacc[t] != 0.f) atomicAdd(&counts[g0 + t], Cacc[t]);
  }
}

// ---------------- K0b: repr = pool / max(counts,1) ----------------
__global__ void k0b_div(const float* __restrict__ pool, const float* __restrict__ counts,
                        float* __restrict__ repr){
  size_t i = (size_t)blockIdx.x * 256 + threadIdx.x;
  int g = (int)(i >> 8);
  repr[i] = pool[i] / fmaxf(counts[g], 1.f);
}

// ---------------- KT: hg[g] = W1 * bf16(repr[g]) + b1 ----------------
__global__ __launch_bounds__(256) void kT_hg(const float* __restrict__ repr,
    const short* __restrict__ w1bf, const float* __restrict__ b1,
    float* __restrict__ hg){
  __shared__ short Ar[16][H + 8];
  const int t    = threadIdx.x;
  const int wid  = t >> 6;
  const int lane = t & 63;
  const int l15  = lane & 15;
  const int l4   = lane >> 4;
  const int g0   = blockIdx.x * 16;

  for (int u = t; u < 16*32; u += 256){
    int row = u >> 5, cg = u & 31;
    int c0 = cg * 8;
    const float4* rp = (const float4*)(repr + (size_t)(g0+row)*H + c0);
    float4 r0 = rp[0], r1 = rp[1];
    bf16x8 o;
    o[0]=f2bf(r0.x); o[1]=f2bf(r0.y); o[2]=f2bf(r0.z); o[3]=f2bf(r0.w);
    o[4]=f2bf(r1.x); o[5]=f2bf(r1.y); o[6]=f2bf(r1.z); o[7]=f2bf(r1.w);
    *(bf16x8*)(&Ar[row][c0]) = o;
  }
  __syncthreads();

  f32x4 acc[4];
  #pragma unroll
  for (int i = 0; i < 4; ++i) acc[i] = (f32x4){0.f,0.f,0.f,0.f};
  #pragma unroll
  for (int kc = 0; kc < 8; ++kc){
    bf16x8 a = *(bf16x8*)(&Ar[l15][kc*32 + l4*8]);
    #pragma unroll
    for (int nt = 0; nt < 4; ++nt){
      int col = wid*64 + nt*16 + l15;
      bf16x8 b = *(const bf16x8*)(w1bf + (size_t)col*H + kc*32 + l4*8);
      acc[nt] = __builtin_amdgcn_mfma_f32_16x16x32_bf16(a, b, acc[nt], 0, 0, 0);
    }
  }
  #pragma unroll
  for (int nt = 0; nt < 4; ++nt){
    int col = wid*64 + nt*16 + l15;
    float b1v = b1[col];
    #pragma unroll
    for (int j = 0; j < 4; ++j){
      int row = l4*4 + j;
      hg[(size_t)(g0+row)*H + col] = acc[nt][j] + b1v;
    }
  }
}

// ---------------- K1: persistent fused gate MLP + weighted pooling ----------------
// h = relu(W1*bf16(x) + hg[g]); gate = sigmoid(w2.h + b2); pool[g] += gate * bf16(x)
template<bool BF>
__global__ __launch_bounds__(512, 4) void k1_gate(
    const float* __restrict__ xf32, const short* __restrict__ xbf,
    const int* __restrict__ batch, const float* __restrict__ hg,
    const short* __restrict__ w1bf, const float* __restrict__ w2,
    const float* __restrict__ b2p, float* __restrict__ pool,
    int nNodes, int nTiles, int tilesPerBlk){

  __shared__ short Ain[TK][H + 8];        // 16.9 KB
  __shared__ float Pacc[16][H];           // 16 KB sliding-window accumulator
  __shared__ float partials[8][TK];       // 1 KB
  __shared__ float gates[TK];
  __shared__ int   ngS[TK];

  const int t    = threadIdx.x;
  const int wid  = t >> 6;      // 0..7 : col-block of 32
  const int lane = t & 63;
  const int l15  = lane & 15;
  const int l4   = lane >> 4;

  const int tile0 = blockIdx.x * tilesPerBlk;
  if (tile0 >= nTiles) return;
  const int tile1 = (tile0 + tilesPerBlk < nTiles) ? tile0 + tilesPerBlk : nTiles;

  for (int u = t; u < 16*H; u += 512) ((float*)Pacc)[u] = 0.f;

  // W1 slices for this wave's 32 output cols, in registers (loaded once per block)
  bf16x8 Bf0[8], Bf1[8];
  {
    const short* wp0 = w1bf + (size_t)(wid*32 + l15)*H + l4*8;
    #pragma unroll
    for (int kc = 0; kc < 8; ++kc){
      Bf0[kc] = *(const bf16x8*)(wp0 + kc*32);
      Bf1[kc] = *(const bf16x8*)(wp0 + 16*H + kc*32);
    }
  }
  const float w2v0 = w2[wid*32 + l15];
  const float w2v1 = w2[wid*32 + 16 + l15];
  const float b2v  = b2p[0];

  int gw0 = batch[tile0 * TK];   // window base (block-uniform)

  // ---- prefetch state ----
  bf16x8 xv[2];
  float4 xf[2][2];
  int ngv = -1;

  auto issue = [&](int tile){
    int base = tile * TK;
    #pragma unroll
    for (int q = 0; q < 2; ++q){
      int u = t + q*512, row = u >> 5, cg = u & 31;
      int node = base + row;
      if constexpr (BF){
        if (node < nNodes) xv[q] = *(const bf16x8*)(xbf + (size_t)node*H + cg*8);
        else xv[q] = (bf16x8)0;
      } else {
        if (node < nNodes){
          const float4* xp = (const float4*)(xf32 + (size_t)node*H + cg*8);
          xf[q][0] = xp[0]; xf[q][1] = xp[1];
        } else { xf[q][0] = make_float4(0.f,0.f,0.f,0.f); xf[q][1] = make_float4(0.f,0.f,0.f,0.f); }
      }
    }
    if (t < TK){
      int node = base + t;
      ngv = (node < nNodes) ? batch[node] : -1;
    }
  };
  issue(tile0);

  for (int tile = tile0; tile < tile1; ++tile){
    ldsbar();   // B1: previous pooling / Pacc-zero visible; Ain,ngS writable

    // write staged tile to LDS
    #pragma unroll
    for (int q = 0; q < 2; ++q){
      int u = t + q*512, row = u >> 5, cg = u & 31;
      bf16x8 o;
      if constexpr (BF) o = xv[q];
      else {
        float4 a = xf[q][0], b = xf[q][1];
        o[0]=f2bf(a.x); o[1]=f2bf(a.y); o[2]=f2bf(a.z); o[3]=f2bf(a.w);
        o[4]=f2bf(b.x); o[5]=f2bf(b.y); o[6]=f2bf(b.z); o[7]=f2bf(b.w);
      }
      *(bf16x8*)(&Ain[row][cg*8]) = o;
    }
    if (t < TK) ngS[t] = ngv;
    ldsbar();   // B2: Ain + ngS visible

    // issue prefetch of next tile (stays in flight across lgkm-only barriers)
    if (tile + 1 < tile1) issue(tile + 1);

    // ---- sliding-window management (block-uniform) ----
    int gfirst = ngS[0];
    int glast;
    if (tile*TK + TK <= nNodes) glast = ngS[TK-1];
    else {
      glast = gfirst;
      for (int i = TK-1; i > 0; --i){ int g = ngS[i]; if (g >= 0){ glast = g; break; } }
    }
    if (gfirst >= 0 && glast >= gw0 + 16){
      for (int u = t; u < 16*H; u += 512){
        float vv = ((float*)Pacc)[u];
        if (vv != 0.f){
          int r = u >> 8, c = u & 255;
          atomicAdd(&pool[(size_t)(gw0 + r)*H + c], vv);
          ((float*)Pacc)[u] = 0.f;
        }
      }
      gw0 = gfirst;
      ldsbar(); // zeros visible before new accumulation
    }

    // ---- MFMA: rows 0..31, cols wid*32..+32 ----
    f32x4 acc0[2], acc1[2];
    #pragma unroll
    for (int r = 0; r < 2; ++r){ acc0[r] = (f32x4){0.f,0.f,0.f,0.f}; acc1[r] = (f32x4){0.f,0.f,0.f,0.f}; }
    #pragma unroll
    for (int kc = 0; kc < 8; ++kc){
      #pragma unroll
      for (int r = 0; r < 2; ++r){
        bf16x8 a = *(bf16x8*)(&Ain[r*16 + l15][kc*32 + l4*8]);
        acc0[r] = __builtin_amdgcn_mfma_f32_16x16x32_bf16(a, Bf0[kc], acc0[r], 0, 0, 0);
        acc1[r] = __builtin_amdgcn_mfma_f32_16x16x32_bf16(a, Bf1[kc], acc1[r], 0, 0, 0);
      }
    }

    // ---- epilogue: partial w2·relu(acc + hg[g][col]) with per-thread g caching ----
    float p[2][4];
    {
      int gprev = -1; float hv0 = 0.f, hv1 = 0.f;
      #pragma unroll
      for (int r = 0; r < 2; ++r){
        #pragma unroll
        for (int j = 0; j < 4; ++j){
          int row = r*16 + l4*4 + j;
          int g = ngS[row];
          float val = 0.f;
          if (g >= 0){
            if (g != gprev){
              const float* hgr = hg + (size_t)g*H + wid*32;
              hv0 = hgr[l15]; hv1 = hgr[16 + l15];
              gprev = g;
            }
            float h0 = fmaxf(acc0[r][j] + hv0, 0.f);
            float h1 = fmaxf(acc1[r][j] + hv1, 0.f);
            val = w2v0*h0 + w2v1*h1;
          }
          p[r][j] = val;
        }
      }
    }
    #pragma unroll
    for (int off = 1; off < 16; off <<= 1){
      #pragma unroll
      for (int r = 0; r < 2; ++r)
        #pragma unroll
        for (int j = 0; j < 4; ++j) p[r][j] += __shfl_xor(p[r][j], off);
    }
    if (l15 == 0){
      #pragma unroll
      for (int r = 0; r < 2; ++r)
        #pragma unroll
        for (int j = 0; j < 4; ++j) partials[wid][r*16 + l4*4 + j] = p[r][j];
    }
    ldsbar();   // B3

    if (t < TK){
      float s = b2v;
      #pragma unroll
      for (int w = 0; w < 8; ++w) s += partials[w][t];
      gates[t] = sigmoidf_(s);
    }
    ldsbar();   // B4

    // ---- weighted pooling into sliding-window Pacc ----
    {
      const int c2 = (t & 127) * 2;
      const int rg = t >> 7;      // 0..3 : 8 rows each
      const int r0 = rg * 8;

      float ax = 0.f, ay = 0.f;
      int cur = ngS[r0];
      if (cur >= 0){
        #pragma unroll
        for (int i = 0; i < 8; ++i){
          int g = ngS[r0 + i];
          if (g < 0) break;
          if (g != cur){
            int idx = cur - gw0;
            if (idx >= 0 && idx < 16){ atomicAdd(&Pacc[idx][c2], ax); atomicAdd(&Pacc[idx][c2+1], ay); }
            else { atomicAdd(&pool[(size_t)cur*H + c2], ax); atomicAdd(&pool[(size_t)cur*H + c2+1], ay); }
            ax = ay = 0.f; cur = g;
          }
          uint32_t av = *(const uint32_t*)(&Ain[r0 + i][c2]);
          float gv = gates[r0 + i];
          ax += gv * bf2f((short)(uint16_t)(av & 0xFFFFu));
          ay += gv * bf2f((short)(uint16_t)(av >> 16));
        }
        int idx = cur - gw0;
        if (idx >= 0 && idx < 16){ atomicAdd(&Pacc[idx][c2], ax); atomicAdd(&Pacc[idx][c2+1], ay); }
        else { atomicAdd(&pool[(size_t)cur*H + c2], ax); atomicAdd(&pool[(size_t)cur*H + c2+1], ay); }
      }
    }
  }

  // final window flush
  ldsbar();
  for (int u = t; u < 16*H; u += 512){
    float vv = ((float*)Pacc)[u];
    if (vv != 0.f){
      int r = u >> 8, c = u & 255;
      atomicAdd(&pool[(size_t)(gw0 + r)*H + c], vv);
    }
  }
}

// ---------------- K2: fused GRU over 16 graphs/block ----------------
__global__ __launch_bounds__(256) void k2_gru(const float* __restrict__ pool,
    const float* __restrict__ counts, const float* __restrict__ repr_in,
    const short* __restrict__ wihbf, const short* __restrict__ whhbf,
    const float* __restrict__ bih, const float* __restrict__ bhh,
    float* __restrict__ repr_out){

  __shared__ short Anew[16][H + 8];
  __shared__ short Aold[16][H + 8];
  __shared__ float hold[16][H];
  __shared__ float srz[16][2*H];
  __shared__ float sni[16][H];
  __shared__ float snh[16][H];

  const int t    = threadIdx.x;
  const int wid  = t >> 6;
  const int lane = t & 63;
  const int l15  = lane & 15;
  const int l4   = lane >> 4;
  const int g0   = blockIdx.x * 16;

  for (int u = t; u < 16*H; u += 256){
    int row = u >> 8, c = u & 255;
    int g = g0 + row;
    float cnt = fmaxf(counts[g], 1.f);
    float rin = repr_in[(size_t)g*H + c];
    float nr  = pool[(size_t)g*H + c] / cnt;
    Anew[row][c] = f2bf(nr);
    Aold[row][c] = f2bf(rin);
    hold[row][c] = rin;
  }
  __syncthreads();

  f32x4 ai[12], ah[12];
  #pragma unroll
  for (int i = 0; i < 12; ++i){ ai[i] = (f32x4){0.f,0.f,0.f,0.f}; ah[i] = (f32x4){0.f,0.f,0.f,0.f}; }

  for (int kc = 0; kc < 8; ++kc){
    bf16x8 an = *(bf16x8*)(&Anew[l15][kc*32 + l4*8]);
    bf16x8 ao = *(bf16x8*)(&Aold[l15][kc*32 + l4*8]);
    #pragma unroll
    for (int nt = 0; nt < 12; ++nt){
      int n = wid*192 + nt*16 + l15;
      bf16x8 bi = *(const bf16x8*)(wihbf + (size_t)n*H + kc*32 + l4*8);
      bf16x8 bh = *(const bf16x8*)(whhbf + (size_t)n*H + kc*32 + l4*8);
      ai[nt] = __builtin_amdgcn_mfma_f32_16x16x32_bf16(an, bi, ai[nt], 0, 0, 0);
      ah[nt] = __builtin_amdgcn_mfma_f32_16x16x32_bf16(ao, bh, ah[nt], 0, 0, 0);
    }
  }

  #pragma unroll
  for (int nt = 0; nt < 12; ++nt){
    int n = wid*192 + nt*16 + l15;
    float bi = bih[n], bh = bhh[n];
    #pragma unroll
    for (int r = 0; r < 4; ++r){
      int row = l4*4 + r;
      float si = ai[nt][r] + bi;
      float sh = ah[nt][r] + bh;
      if (n < 2*H) srz[row][n] = si + sh;
      else { sni[row][n - 2*H] = si; snh[row][n - 2*H] = sh; }
    }
  }
  __syncthreads();

  for (int u = t; u < 16*H; u += 256){
    int row = u >> 8, c = u & 255;
    float rr = sigmoidf_(srz[row][c]);
    float zz = sigmoidf_(srz[row][H + c]);
    float nn = tanhf(sni[row][c] + rr * snh[row][c]);
    float hv = (1.f - zz) * nn + zz * hold[row][c];
    repr_out[(size_t)(g0 + row)*H + c] = fmaxf(hv, 0.f);
  }
}

extern "C" void kernel_launch(void* const* d_in, const int* in_sizes, int n_in,
                              void* d_out, int out_size, void* d_ws, size_t ws_size,
                              hipStream_t stream){
  const float* x    = (const float*)d_in[0];
  const float* w1   = (const float*)d_in[1];
  const float* b1   = (const float*)d_in[2];
  const float* w2   = (const float*)d_in[3];
  const float* b2   = (const float*)d_in[4];
  const float* wih  = (const float*)d_in[5];
  const float* whh  = (const float*)d_in[6];
  const float* bih  = (const float*)d_in[7];
  const float* bhh  = (const float*)d_in[8];
  const int*   batch= (const int*)d_in[9];
  const int N = in_sizes[9];

  char* ws = (char*)d_ws;
  short* w1bf   = (short*)(ws + 0);            // 128 KB
  short* wihbf  = (short*)(ws + (1u<<17));     // 384 KB @128K
  short* whhbf  = (short*)(ws + (1u<<19));     // 384 KB @512K
  float* counts = (float*)(ws + 917504);       // 16 KB @896K
  float* pool   = (float*)(ws + (1u<<20));     // 4 MB @1M
  float* repr   = (float*)(ws + (1u<<20) + (1u<<22)); // 4 MB @5M
  float* hg     = (float*)d_out;               // 4 MB, dead before final k2 writes output
  float* outp   = (float*)d_out;

  const size_t XBF_OFF = (size_t)16u << 20;    // 16 MB
  const bool useXbf = ws_size >= XBF_OFF + (size_t)N * H * sizeof(short);
  short* xbf = useXbf ? (short*)(ws + XBF_OFF) : nullptr;

  const int nTiles  = (N + TK - 1) / TK;       // 15625
  const int nBlkK1  = 768;
  const int tilesPB = (nTiles + nBlkK1 - 1) / nBlkK1;
  const int nBlk0   = (N + T0 - 1) / T0;

  conv_w<<<768, 256, 0, stream>>>(w1, wih, whh, w1bf, wihbf, whhbf);

  hipMemsetAsync(counts, 0, G*sizeof(float), stream);
  hipMemsetAsync(pool, 0, (size_t)G*H*sizeof(float), stream);
  k0_pool<<<nBlk0, 512, 0, stream>>>(x, batch, pool, counts, xbf, N);
  k0b_div<<<G*H/256, 256, 0, stream>>>(pool, counts, repr);

  for (int ts = 0; ts < 2; ++ts){
    kT_hg<<<G/16, 256, 0, stream>>>(repr, w1bf, b1, hg);
    hipMemsetAsync(pool, 0, (size_t)G*H*sizeof(float), stream);
    if (useXbf)
      k1_gate<true><<<nBlkK1, 512, 0, stream>>>(x, xbf, batch, hg, w1bf, w2, b2, pool, N, nTiles, tilesPB);
    else
      k1_gate<false><<<nBlkK1, 512, 0, stream>>>(x, xbf, batch, hg, w1bf, w2, b2, pool, N, nTiles, tilesPB);
    k2_gru<<<G/16, 256, 0, stream>>>(pool, counts, repr, wihbf, whhbf, bih, bhh,
                                     (ts == 0) ? repr : outp);
  }
}